// Round 10
// baseline (730.847 us; speedup 1.0000x reference)
//
#include <hip/hip_runtime.h>
#include <hip/hip_fp16.h>
#include <hip/hip_cooperative_groups.h>

#define KAPPA 0.99f
#define T_MAX 32

typedef unsigned short u16;
typedef _Float16 f16x8 __attribute__((ext_vector_type(8)));
typedef float f32x4 __attribute__((ext_vector_type(4)));

static __device__ __forceinline__ f16x8 bc16(uint4 u) {
  union { uint4 a; f16x8 b; } x;
  x.a = u;
  return x.b;
}

// ---------- Projection of each row of W onto the L1 ball of radius KAPPA ----------
__global__ __launch_bounds__(64) void proj_kernel(const float* __restrict__ W,
                                                  u16* __restrict__ Wp16) {
  __shared__ float a[128];
  __shared__ float css[128];
  __shared__ float s_alpha, s_l1;
  int row = blockIdx.x;
  int t = threadIdx.x;
  a[t]      = fabsf(W[row * 128 + t]);
  a[t + 64] = fabsf(W[row * 128 + t + 64]);
  __syncthreads();
  for (int k = 2; k <= 128; k <<= 1) {
    for (int j = k >> 1; j > 0; j >>= 1) {
      int i = 2 * t - (t & (j - 1));
      int ixj = i ^ j;
      bool up = ((i & k) == 0);
      float x = a[i], y = a[ixj];
      if ((x > y) == up) { a[i] = y; a[ixj] = x; }
      __syncthreads();
    }
  }
  if (t == 0) {
    float csum = 0.f;
    int cnt = 0;
    for (int j = 0; j < 128; ++j) {
      float ad = a[127 - j];
      csum += ad;
      float c = csum - KAPPA;
      css[j] = c;
      if (ad * (float)(j + 1) > c) cnt++;
    }
    s_alpha = css[cnt - 1] / (float)cnt;
    s_l1 = csum;
  }
  __syncthreads();
  float alpha = s_alpha;
  bool doproj = (s_l1 > KAPPA);
  for (int idx = t; idx < 128; idx += 64) {
    float w = W[row * 128 + idx];
    float pp = fmaxf(fabsf(w) - alpha, 0.f);
    float res = doproj ? ((w >= 0.f) ? pp : -pp) : w;
    Wp16[row * 128 + idx] = __half_as_ushort(__float2half_rn(res));
  }
}

// repack Wp16 into MFMA A-fragment order (frag = mt*4+kt)
__global__ __launch_bounds__(256) void wpa_kernel(const u16* __restrict__ Wp16,
                                                  u16* __restrict__ WpA) {
  int idx = blockIdx.x * 256 + threadIdx.x;  // < 2048
  int l = idx & 63, frag = idx >> 6;
  int mt = frag >> 2, kt = frag & 3;
  int m = mt * 16 + (l & 15);
  int k0 = kt * 32 + (l >> 4) * 8;
  u16* dst = WpA + (size_t)idx * 8;
#pragma unroll
  for (int i = 0; i < 8; ++i) dst[i] = Wp16[m * 128 + k0 + i];
}

// ---------- 128x128 transpose (Omega -> OmegaT, fp32) ----------
__global__ __launch_bounds__(256) void transpose128(const float* __restrict__ A,
                                                    float* __restrict__ AT) {
  int idx = blockIdx.x * 256 + threadIdx.x;
  int f = idx >> 7, p = idx & 127;
  AT[p * 128 + f] = A[idx];
}

// ---------- CSR build ----------
// 8-way split histogram (R9-verified: hist ~36.5us -> off the top-5 list).
__global__ __launch_bounds__(256) void hist_kernel(const int* __restrict__ col,
                                                   int* __restrict__ counts8,
                                                   int N, int E) {
  int e = blockIdx.x * 256 + threadIdx.x;
  if (e < E) atomicAdd(&counts8[(blockIdx.x & 7) * (N + 1) + col[e]], 1);
}

__global__ __launch_bounds__(256) void scanA(const int* __restrict__ counts8,
                                             int* __restrict__ offs,
                                             int* __restrict__ bsums, int N) {
  __shared__ int tmp[256];
  int t = threadIdx.x, i = blockIdx.x * 256 + t;
  int v = 0;
  if (i < N) {
#pragma unroll
    for (int g = 0; g < 8; ++g) v += counts8[g * (N + 1) + i];
  }
  tmp[t] = v;
  __syncthreads();
  for (int d = 1; d < 256; d <<= 1) {
    int u = (t >= d) ? tmp[t - d] : 0;
    __syncthreads();
    tmp[t] += u;
    __syncthreads();
  }
  if (i < N) offs[i] = tmp[t] - v;
  if (t == 255) bsums[blockIdx.x] = tmp[255];
}

__global__ __launch_bounds__(256) void scanB(int* __restrict__ bsums, int nb) {
  __shared__ int tmp[256];
  int t = threadIdx.x;
  int v = (t < nb) ? bsums[t] : 0;
  tmp[t] = v;
  __syncthreads();
  for (int d = 1; d < 256; d <<= 1) {
    int u = (t >= d) ? tmp[t - d] : 0;
    __syncthreads();
    tmp[t] += u;
    __syncthreads();
  }
  if (t < nb) bsums[t] = tmp[t] - v;
}

__global__ __launch_bounds__(256) void scanC(int* __restrict__ offs,
                                             const int* __restrict__ bsums,
                                             int* __restrict__ cursors, int N, int E) {
  int i = blockIdx.x * 256 + threadIdx.x;
  if (i < N) {
    int o = offs[i] + bsums[blockIdx.x];
    offs[i] = o;
    cursors[i] = o;
  }
  if (i == 0) offs[N] = E;
}

// packed (row, val) per edge
__global__ __launch_bounds__(256) void scatter_kernel(const int* __restrict__ erow,
                                                      const int* __restrict__ ecol,
                                                      const float* __restrict__ eval,
                                                      int* __restrict__ cursors,
                                                      int2* __restrict__ cpair, int E) {
  int e = blockIdx.x * 256 + threadIdx.x;
  if (e < E) {
    int c = ecol[e];
    int pos = atomicAdd(&cursors[c], 1);
    cpair[pos] = make_int2(erow[e], __float_as_int(eval[e]));
  }
}

// ================= device helpers =================

__device__ __forceinline__ void store_half16(u16* dst, const float* acc) {
  union { u16 us[16]; uint4 q[2]; } pk;
#pragma unroll
  for (int k = 0; k < 16; ++k) pk.us[k] = __half_as_ushort(__float2half_rn(acc[k]));
  uint4* d4 = (uint4*)dst;
  d4[0] = pk.q[0];
  d4[1] = pk.q[1];
}

// Phase A: Yh = fp16(Omega @ U), feature-major U read
__device__ __forceinline__ void u_gemm_phase(const float* __restrict__ U,
                                             const float* __restrict__ OmT,
                                             u16* __restrict__ Yh, int N, int ntiles,
                                             int bid, int nblocks, int tid) {
  int n = tid & 63;
  int fg = __builtin_amdgcn_readfirstlane(tid >> 6);
  for (int tile = bid; tile < ntiles; tile += nblocks) {
    int node = tile * 64 + n;
    int nc = min(node, N - 1);
    float acc[16];
#pragma unroll
    for (int k = 0; k < 16; ++k) acc[k] = 0.f;
    for (int j = 0; j < 128; ++j) {
      float x = U[(size_t)j * N + nc];
      const float* wr = OmT + j * 128 + fg * 16;
#pragma unroll
      for (int k = 0; k < 16; ++k) acc[k] = fmaf(wr[k], x, acc[k]);
    }
    if (node < N) store_half16(Yh + (size_t)node * 128 + fg * 16, acc);
  }
}

// 8-way-split error slots: max over groups
__device__ __forceinline__ float err_at(const unsigned* __restrict__ errs, int t) {
  unsigned m = 0u;
#pragma unroll
  for (int g = 0; g < 8; ++g) {
    unsigned v = __hip_atomic_load(errs + t * 8 + g, __ATOMIC_RELAXED,
                                   __HIP_MEMORY_SCOPE_AGENT);
    m = (v > m) ? v : m;
  }
  return __uint_as_float(m);
}

// stop rule, robust to the fp16 quantization floor (all passing runs landed
// absmax at the fp16 floor 2^-9)
__device__ __forceinline__ bool stop_rule(float e, float prev) {
  return (e < 2e-3f) || (e < 4e-3f && e < 0.6f * prev) ||
         (e < 3e-3f && e > 0.9f * prev);
}

__device__ __forceinline__ void load_afrags(const u16* __restrict__ WpA, int wave,
                                            int lane, f16x8* afrag) {
  const uint4* ag = (const uint4*)WpA;
#pragma unroll
  for (int kt = 0; kt < 4; ++kt) afrag[kt] = bc16(ag[(wave * 4 + kt) * 64 + lane]);
}

// Per-row gather (R1-verified fastest at persistent-kernel occupancy):
// 16-deep + 8-deep UNPREDICATED bodies (no per-element clamp/select VALU),
// one clamped-8 predicated tail. R9's lockstep 4-row variant cost +3 VALU ops
// per element -> VALUBusy 19% vs 16.2%, solve 624 vs 579.
__device__ __forceinline__ float2 gather_row(const __half2* __restrict__ Y2,
                                             const int* __restrict__ offs,
                                             const int2* __restrict__ cpair,
                                             int c, int lane) {
  int beg = offs[c], end = offs[c + 1];
  float ax[4] = {0.f, 0.f, 0.f, 0.f};
  float ay[4] = {0.f, 0.f, 0.f, 0.f};
  int e = beg;
  for (; e + 15 < end; e += 16) {  // 16 gathers in flight
    int2 p[16];
#pragma unroll
    for (int i = 0; i < 16; ++i) p[i] = cpair[e + i];
    __half2 h[16];
#pragma unroll
    for (int i = 0; i < 16; ++i) h[i] = Y2[(size_t)p[i].x * 64 + lane];
#pragma unroll
    for (int i = 0; i < 16; ++i) {
      float v = __int_as_float(p[i].y);
      ax[i & 3] = fmaf(v, __low2float(h[i]), ax[i & 3]);
      ay[i & 3] = fmaf(v, __high2float(h[i]), ay[i & 3]);
    }
  }
  for (; e + 7 < end; e += 8) {
    int2 p[8];
#pragma unroll
    for (int i = 0; i < 8; ++i) p[i] = cpair[e + i];
    __half2 h[8];
#pragma unroll
    for (int i = 0; i < 8; ++i) h[i] = Y2[(size_t)p[i].x * 64 + lane];
#pragma unroll
    for (int i = 0; i < 8; ++i) {
      float v = __int_as_float(p[i].y);
      ax[i & 3] = fmaf(v, __low2float(h[i]), ax[i & 3]);
      ay[i & 3] = fmaf(v, __high2float(h[i]), ay[i & 3]);
    }
  }
  int rem = end - e;
  if (rem > 0) {  // clamped, predicated tail: one latency exposure
    int2 p[8];
#pragma unroll
    for (int i = 0; i < 8; ++i) {
      int ee = e + i;
      p[i] = cpair[ee < end ? ee : end - 1];
    }
    __half2 h[8];
#pragma unroll
    for (int i = 0; i < 8; ++i) h[i] = Y2[(size_t)p[i].x * 64 + lane];
#pragma unroll
    for (int i = 0; i < 8; ++i) {
      float v = (i < rem) ? __int_as_float(p[i].y) : 0.f;
      ax[i & 3] = fmaf(v, __low2float(h[i]), ax[i & 3]);
      ay[i & 3] = fmaf(v, __high2float(h[i]), ay[i & 3]);
    }
  }
  return make_float2((ax[0] + ax[1]) + (ax[2] + ax[3]),
                     (ay[0] + ay[1]) + (ay[2] + ay[3]));
}

// Fused pass over statically partitioned 32-node tiles. Double-buffered
// synchronous Jacobi (R1's proven-fastest structure).
// mode 0 (seed): B=gather(Y); Bh=Xh=fp16(B); Ydst=fp16(Wp@B)
// mode 1 (step): x=relu(gather(Y)+B); err vs Xh; Xh=fp16(x); Ydst=fp16(Wp@x)
__device__ __forceinline__ void fused_tile_pass(
    const u16* __restrict__ Ysrc, u16* __restrict__ Ydst,
    const int* __restrict__ offs, const int2* __restrict__ cpair,
    u16* __restrict__ Bh, u16* __restrict__ Xh, int N, int mode,
    unsigned* err_slot, const f16x8* afrag, __half2 (*xs)[72],
    float* werr, int bid, int nblocks, int tid, int lane, int wave) {
  const __half2* Y2 = (const __half2*)Ysrc;
  __half2* B2 = (__half2*)Bh;
  __half2* X2 = (__half2*)Xh;
  int ntiles = (N + 31) >> 5;
  float m = 0.f;
  for (int tile = bid; tile < ntiles; tile += nblocks) {
    __syncthreads();  // prev tile's MFMA reads of xs done
    int base = tile * 32;
#pragma unroll
    for (int q = 0; q < 4; ++q) {
      int nl = wave * 4 + q;
      int c = base + nl;
      if (c < N) {  // wave-uniform branch
        float2 s = gather_row(Y2, offs, cpair, c, lane);
        float ax = s.x, ay = s.y;
        size_t wi = (size_t)c * 64 + lane;
        if (mode == 0) {
          __half2 hh = __floats2half2_rn(ax, ay);
          B2[wi] = hh;
          X2[wi] = hh;
          xs[nl][lane] = hh;
        } else {
          __half2 b = B2[wi];
          ax = fmaxf(ax + __low2float(b), 0.f);
          ay = fmaxf(ay + __high2float(b), 0.f);
          __half2 xo = X2[wi];
          m = fmaxf(m, fmaxf(fabsf(ax - __low2float(xo)),
                             fabsf(ay - __high2float(xo))));
          __half2 hh = __floats2half2_rn(ax, ay);
          X2[wi] = hh;
          xs[nl][lane] = hh;
        }
      }
    }
    __syncthreads();
    // MFMA: wave w computes M-tile w of Wp @ X(128x32)
    f32x4 acc0 = {0.f, 0.f, 0.f, 0.f};
    f32x4 acc1 = {0.f, 0.f, 0.f, 0.f};
    int nA = lane & 15;
    int q4 = (lane >> 4) * 4;
#pragma unroll
    for (int kt = 0; kt < 4; ++kt) {
      int h0 = kt * 16 + q4;
      f16x8 b0 = bc16(*(const uint4*)&xs[nA][h0]);
      f16x8 b1 = bc16(*(const uint4*)&xs[16 + nA][h0]);
      acc0 = __builtin_amdgcn_mfma_f32_16x16x32_f16(afrag[kt], b0, acc0, 0, 0, 0);
      acc1 = __builtin_amdgcn_mfma_f32_16x16x32_f16(afrag[kt], b1, acc1, 0, 0, 0);
    }
    // D layout: col=lane&15 (node), row=(lane>>4)*4+reg (feat in M-tile)
    int fb = wave * 16 + q4;
    int n0 = base + nA;
    if (n0 < N) {
      __half2* d = (__half2*)(Ydst + (size_t)n0 * 128 + fb);
      d[0] = __floats2half2_rn(acc0.x, acc0.y);
      d[1] = __floats2half2_rn(acc0.z, acc0.w);
    }
    int n1 = base + 16 + nA;
    if (n1 < N) {
      __half2* d = (__half2*)(Ydst + (size_t)n1 * 128 + fb);
      d[0] = __floats2half2_rn(acc1.x, acc1.y);
      d[1] = __floats2half2_rn(acc1.z, acc1.w);
    }
  }
  if (mode == 1) {
#pragma unroll
    for (int o = 32; o > 0; o >>= 1) m = fmaxf(m, __shfl_xor(m, o, 64));
    if (lane == 0) werr[wave] = m;
    __syncthreads();
    if (tid == 0) {
      float bm = werr[0];
#pragma unroll
      for (int w = 1; w < 8; ++w) bm = fmaxf(bm, werr[w]);
      atomicMax(err_slot + (bid & 7), __float_as_uint(bm));  // 8-way split
    }
  }
}

// Output pass: out[f][node] = float(Xh[node][f]), transposed via LDS.
// Tile partition matches fused_tile_pass: block reads only rows it wrote.
__device__ __forceinline__ void xh_transpose_pass(const u16* __restrict__ Xh,
                                                  float* __restrict__ out, int N,
                                                  float (*Ts)[129], int bid,
                                                  int nblocks, int tid) {
  const uint4* X4 = (const uint4*)Xh;  // 16 uint4 per 128-feat row
  int ntiles = (N + 31) >> 5;
  for (int tile = bid; tile < ntiles; tile += nblocks) {
    __syncthreads();
    int base = tile * 32;
    {
      int nn = tid >> 4, cc = tid & 15;  // 512 threads = 32 rows x 16 uint4
      uint4 q = make_uint4(0, 0, 0, 0);
      if (base + nn < N) q = X4[(size_t)(base + nn) * 16 + cc];
      f16x8 h = bc16(q);
      float* dst = &Ts[nn][cc * 8];
#pragma unroll
      for (int j = 0; j < 8; ++j) dst[j] = (float)h[j];
    }
    __syncthreads();
    int n = tid & 31, f0 = tid >> 5;
    int node = base + n;
    if (node < N) {
#pragma unroll
      for (int k = 0; k < 8; ++k) {
        int f = f0 + k * 16;
        out[(size_t)f * N + node] = Ts[n][f];
      }
    }
  }
}

// ================= cooperative solver (R1 structure: cg.sync per sweep) =======
// Barrier ledger (measured): cg.sync ~26-28us; custom two-level relaxed/acq
// variants 40-57us or livelock; kernel-boundary = L2 cold (+170us/pass).
// cg.sync is the floor on this chip; sweeps (~14us) sit near the cross-XCD
// L2/L3-traffic limit (~210 MB/sweep).
__global__ __launch_bounds__(512, 4) void solve_kernel(
    const float* __restrict__ U, const float* __restrict__ OmT,
    const u16* __restrict__ WpA, const int* __restrict__ offs,
    const int2* __restrict__ cpair, u16* __restrict__ Ya, u16* __restrict__ Yb,
    u16* __restrict__ Bh, u16* __restrict__ Xh, float* __restrict__ out,
    unsigned* __restrict__ errs, int N) {
  cooperative_groups::grid_group grid = cooperative_groups::this_grid();
  __shared__ __align__(16) char lds_raw[32 * 129 * 4];  // Ts(16512) >= xs(9216)
  __shared__ float werr[8];
  __shared__ float s_e;
  __half2 (*xs)[72] = (__half2(*)[72])lds_raw;
  float (*Ts)[129] = (float(*)[129])lds_raw;
  const int tid = threadIdx.x;
  const int bid = blockIdx.x, nblocks = gridDim.x;
  const int lane = tid & 63, wave = tid >> 6;
  const int ntiles64 = (N + 63) >> 6;

  f16x8 afrag[4];
  load_afrags(WpA, wave, lane, afrag);

  u_gemm_phase(U, OmT, Ya, N, ntiles64, bid, nblocks, tid);
  grid.sync();
  // seed: B = gather(Om@U from Ya); X0 = B; Yb = Wp@B
  fused_tile_pass(Ya, Yb, offs, cpair, Bh, Xh, N, 0, nullptr, afrag, xs, werr,
                  bid, nblocks, tid, lane, wave);
  grid.sync();

  u16* cur = Yb;
  u16* nxt = Ya;
  float prev = 3.0e38f;
  for (int t = 1; t <= T_MAX; ++t) {
    fused_tile_pass(cur, nxt, offs, cpair, Bh, Xh, N, 1, errs + t * 8, afrag, xs,
                    werr, bid, nblocks, tid, lane, wave);
    grid.sync();
    if (tid == 0) s_e = err_at(errs, t);
    __syncthreads();
    float e = s_e;
    u16* tmp = cur; cur = nxt; nxt = tmp;
    if (stop_rule(e, prev)) break;  // grid-uniform: same slots read by all blocks
    prev = e;
  }

  // output X_T directly (block reads only tiles it wrote: no barrier needed)
  xh_transpose_pass(Xh, out, N, Ts, bid, nblocks, tid);
}

// ================= fallback multi-kernel path (R4, known-good) =================
__global__ __launch_bounds__(512) void u_gemm_kernel(const float* __restrict__ U,
                                                     const float* __restrict__ OmT,
                                                     u16* __restrict__ Yh, int N) {
  u_gemm_phase(U, OmT, Yh, N, (N + 63) >> 6, blockIdx.x, gridDim.x, threadIdx.x);
}

__global__ __launch_bounds__(512, 4) void step_kernel(
    const u16* __restrict__ Ysrc, u16* __restrict__ Ydst,
    const u16* __restrict__ WpA, const int* __restrict__ offs,
    const int2* __restrict__ cpair, u16* __restrict__ Bh, u16* __restrict__ Xh,
    int N, unsigned* __restrict__ errs, int* __restrict__ flags, int t, int mode) {
  if (mode == 1 && t > 1) {
    int sf = __hip_atomic_load(&flags[64], __ATOMIC_RELAXED,
                               __HIP_MEMORY_SCOPE_AGENT);
    if (sf != 0 && t > sf) return;
  }
  __shared__ __align__(16) __half2 xs[32][72];
  __shared__ float werr[8];
  int lane = threadIdx.x & 63, wave = threadIdx.x >> 6;
  f16x8 afrag[4];
  load_afrags(WpA, wave, lane, afrag);
  fused_tile_pass(Ysrc, Ydst, offs, cpair, Bh, Xh, N, mode,
                  (mode == 1) ? (errs + t * 8) : nullptr, afrag, xs, werr,
                  blockIdx.x, gridDim.x, threadIdx.x, lane, wave);
  if (mode == 1 && threadIdx.x == 0) {
    __threadfence();
    int old = __hip_atomic_fetch_add(&flags[t], 1, __ATOMIC_ACQ_REL,
                                     __HIP_MEMORY_SCOPE_AGENT);
    if (old == (int)gridDim.x - 1) {
      float e = err_at(errs, t);
      float prev = (t > 1) ? err_at(errs, t - 1) : 3.0e38f;
      int fired = stop_rule(e, prev) ? t : 0;
      if (t == 1)
        __hip_atomic_store(&flags[64], fired, __ATOMIC_RELEASE,
                           __HIP_MEMORY_SCOPE_AGENT);
      else if (fired && __hip_atomic_load(&flags[64], __ATOMIC_RELAXED,
                                          __HIP_MEMORY_SCOPE_AGENT) == 0)
        __hip_atomic_store(&flags[64], fired, __ATOMIC_RELEASE,
                           __HIP_MEMORY_SCOPE_AGENT);
    }
  }
}

__global__ __launch_bounds__(512) void final_kernel(const u16* __restrict__ Xh,
                                                    float* __restrict__ out, int N) {
  __shared__ float Ts[32][129];
  xh_transpose_pass(Xh, out, N, Ts, blockIdx.x, gridDim.x, threadIdx.x);
}

extern "C" void kernel_launch(void* const* d_in, const int* in_sizes, int n_in,
                              void* d_out, int out_size, void* d_ws, size_t ws_size,
                              hipStream_t stream) {
  const float* W     = (const float*)d_in[0];
  const float* Om    = (const float*)d_in[1];
  const float* U     = (const float*)d_in[2];
  const float* evalp = (const float*)d_in[3];
  const int*   erow  = (const int*)d_in[4];
  const int*   ecol  = (const int*)d_in[5];

  int N = in_sizes[2] / 128;
  int E = in_sizes[3];

  char* p = (char*)d_ws;
  auto alloc = [&](size_t bytes) {
    char* r = p;
    p += (bytes + 255) & ~(size_t)255;
    return r;
  };
  u16* Wp16      = (u16*)alloc(128 * 128 * 2);
  u16* WpA       = (u16*)alloc(32 * 64 * 8 * 2);  // MFMA A-fragment layout
  float* OmT     = (float*)alloc(128 * 128 * 4);
  int* counts8   = (int*)alloc((size_t)8 * (N + 1) * 4);  // split histogram
  int* offs      = (int*)alloc((size_t)(N + 1) * 4);
  int* cursors   = (int*)alloc((size_t)N * 4);
  int* bsums     = (int*)alloc(1024 * 4);
  unsigned* errs = (unsigned*)alloc(512 * 4);   // [t*8+group] split err slots
  int* flags     = (int*)alloc(256 * 4);        // fallback arrive/stop state
  int2* cpair    = (int2*)alloc((size_t)E * 8); // packed (row, val_bits)
  u16* Ya        = (u16*)alloc((size_t)N * 128 * 2);
  u16* Yb        = (u16*)alloc((size_t)N * 128 * 2);
  u16* Bh        = (u16*)alloc((size_t)N * 128 * 2);
  u16* Xh        = (u16*)alloc((size_t)N * 128 * 2);
  float* outp    = (float*)d_out;

  (void)hipMemsetAsync(counts8, 0, (size_t)8 * (N + 1) * 4, stream);
  (void)hipMemsetAsync(errs, 0, 512 * 4, stream);
  (void)hipMemsetAsync(flags, 0, 256 * 4, stream);

  proj_kernel<<<128, 64, 0, stream>>>(W, Wp16);
  wpa_kernel<<<8, 256, 0, stream>>>(Wp16, WpA);
  transpose128<<<64, 256, 0, stream>>>(Om, OmT);
  int ebl = (E + 255) / 256;
  int nbl = (N + 255) / 256;  // <=256 (scanB capacity)
  hist_kernel<<<ebl, 256, 0, stream>>>(ecol, counts8, N, E);
  scanA<<<nbl, 256, 0, stream>>>(counts8, offs, bsums, N);
  scanB<<<1, 256, 0, stream>>>(bsums, nbl);
  scanC<<<nbl, 256, 0, stream>>>(offs, bsums, cursors, N, E);
  scatter_kernel<<<ebl, 256, 0, stream>>>(erow, ecol, evalp, cursors, cpair, E);

  // cooperative grid sized from runtime occupancy (pure queries, capture-safe)
  int dev = 0;
  (void)hipGetDevice(&dev);
  int cus = 0;
  if (hipDeviceGetAttribute(&cus, hipDeviceAttributeMultiprocessorCount, dev) != hipSuccess ||
      cus <= 0)
    cus = 256;
  int maxb = 0;
  if (hipOccupancyMaxActiveBlocksPerMultiprocessor(&maxb, (const void*)solve_kernel, 512, 0) !=
          hipSuccess ||
      maxb < 1)
    maxb = 1;
  long grid = (long)maxb * (long)cus;
  if (grid > 1024) grid = 1024;

  void* args[] = {(void*)&U,    (void*)&OmT,  (void*)&WpA, (void*)&offs,
                  (void*)&cpair, (void*)&Ya,  (void*)&Yb,
                  (void*)&Bh,   (void*)&Xh,   (void*)&outp, (void*)&errs,
                  (void*)&N};
  hipError_t ce = hipLaunchCooperativeKernel((void*)solve_kernel, dim3((unsigned)grid),
                                             dim3(512), args, 0, stream);
  if (ce != hipSuccess) {
    // fallback: R4 multi-kernel path (kernel boundary = HW barrier)
    int g32 = (N + 31) / 32;
    u_gemm_kernel<<<1024, 512, 0, stream>>>(U, OmT, Ya, N);
    step_kernel<<<g32, 512, 0, stream>>>(Ya, Yb, WpA, offs, cpair, Bh, Xh, N,
                                         errs, flags, 0, 0);  // seed -> Yb
    u16* cur = Yb; u16* nxt = Ya;
    for (int t = 1; t <= T_MAX; ++t) {
      step_kernel<<<g32, 512, 0, stream>>>(cur, nxt, WpA, offs, cpair, Bh, Xh,
                                           N, errs, flags, t, 1);
      u16* tmp = cur; cur = nxt; nxt = tmp;
    }
    final_kernel<<<g32, 512, 0, stream>>>(Xh, outp, N);
  }
}